// Round 1
// baseline (1193.888 us; speedup 1.0000x reference)
//
#include <hip/hip_runtime.h>
#include <hip/hip_bf16.h>
#include <math.h>

#define NPTS 8192
#define KNN 16
#define CHUNK 128   // query points per block

// One block handles CHUNK query points of one cloud.
// Clouds: 0 = x[b=0], 1 = x[b=1], 2 = y[b=0], 3 = y[b=1].
__global__ __launch_bounds__(CHUNK, 1) void knn_eig_kernel(
    const float* __restrict__ x, const float* __restrict__ y,
    float* __restrict__ er /* [4 * NPTS] */) {

    __shared__ float sx[NPTS];
    __shared__ float sy[NPTS];
    __shared__ float sz[NPTS];
    __shared__ float ssq[NPTS];

    const int blocksPerCloud = NPTS / CHUNK;
    const int cloud = blockIdx.x / blocksPerCloud;
    const int chunk = blockIdx.x % blocksPerCloud;
    const float* src = (cloud < 2 ? x : y) + (size_t)(cloud & 1) * NPTS * 3;

    // Stage the whole cloud into LDS (coords + squared norms).
    for (int i = threadIdx.x; i < NPTS; i += CHUNK) {
        float px = src[i * 3 + 0];
        float py = src[i * 3 + 1];
        float pz = src[i * 3 + 2];
        sx[i] = px; sy[i] = py; sz[i] = pz;
        ssq[i] = px * px + py * py + pz * pz;   // matches jnp.sum(p*p, -1)
    }
    __syncthreads();

    const int q = chunk * CHUNK + threadIdx.x;
    const float qx = sx[q], qy = sy[q], qz = sz[q];
    const float sqq = ssq[q];

    // Sorted (ascending) top-16 distances + indices, fully in registers.
    float dist[KNN];
    int   idx[KNN];
#pragma unroll
    for (int t = 0; t < KNN; ++t) { dist[t] = 3.4e38f; idx[t] = 0; }

    for (int j = 0; j < NPTS; ++j) {
        float cx = sx[j], cy = sy[j], cz = sz[j];
        float dot = qx * cx + qy * cy + qz * cz;
        float d2 = (sqq + ssq[j]) - 2.0f * dot;   // reference formula
        if (d2 < dist[KNN - 1]) {                 // strict <: ties keep lower index (top_k semantics)
            dist[KNN - 1] = d2;
            idx[KNN - 1] = j;
            // bubble the new element up to its sorted position
#pragma unroll
            for (int t = KNN - 1; t > 0; --t) {
                if (dist[t] < dist[t - 1]) {
                    float tv = dist[t]; dist[t] = dist[t - 1]; dist[t - 1] = tv;
                    int   ti = idx[t];  idx[t]  = idx[t - 1];  idx[t - 1]  = ti;
                }
            }
        }
    }

    // Gather the 16 neighbors and compute mean (fp32, like the reference).
    float nx[KNN], ny[KNN], nz[KNN];
    float mx = 0.f, my = 0.f, mz = 0.f;
#pragma unroll
    for (int t = 0; t < KNN; ++t) {
        nx[t] = sx[idx[t]]; ny[t] = sy[idx[t]]; nz[t] = sz[idx[t]];
        mx += nx[t]; my += ny[t]; mz += nz[t];
    }
    mx *= (1.0f / KNN); my *= (1.0f / KNN); mz *= (1.0f / KNN);

    // Covariance (fp32 accumulate, /k).
    float c00 = 0.f, c01 = 0.f, c02 = 0.f, c11 = 0.f, c12 = 0.f, c22 = 0.f;
#pragma unroll
    for (int t = 0; t < KNN; ++t) {
        float dx = nx[t] - mx, dy = ny[t] - my, dz = nz[t] - mz;
        c00 += dx * dx; c01 += dx * dy; c02 += dx * dz;
        c11 += dy * dy; c12 += dy * dz; c22 += dz * dz;
    }
    const float invk = 1.0f / KNN;
    c00 *= invk; c01 *= invk; c02 *= invk;
    c11 *= invk; c12 *= invk; c22 *= invk;

    // Closed-form symmetric 3x3 eigenvalues in fp64 (trigonometric method).
    double a00 = c00, a01 = c01, a02 = c02, a11 = c11, a12 = c12, a22 = c22;
    double qm = (a00 + a11 + a22) * (1.0 / 3.0);
    double p1 = a01 * a01 + a02 * a02 + a12 * a12;
    double b00 = a00 - qm, b11 = a11 - qm, b22 = a22 - qm;
    double p2 = b00 * b00 + b11 * b11 + b22 * b22 + 2.0 * p1;

    double ratio;
    if (p2 <= 0.0) {
        ratio = 1.0;  // isotropic: all eigenvalues equal
    } else {
        double p = sqrt(p2 * (1.0 / 6.0));
        double inv = 1.0 / p;
        double m00 = b00 * inv, m11 = b11 * inv, m22 = b22 * inv;
        double m01 = a01 * inv, m02 = a02 * inv, m12 = a12 * inv;
        double detB = m00 * (m11 * m22 - m12 * m12)
                    - m01 * (m01 * m22 - m12 * m02)
                    + m02 * (m01 * m12 - m11 * m02);
        double r = 0.5 * detB;
        r = fmin(1.0, fmax(-1.0, r));
        double phi = acos(r) * (1.0 / 3.0);
        double e1 = qm + 2.0 * p * cos(phi);                          // lambda_max
        double e3 = qm + 2.0 * p * cos(phi + 2.0943951023931953);     // lambda_min (phi + 2pi/3)
        double e2 = 3.0 * qm - e1 - e3;                               // lambda_mid
        ratio = e1 / e2;
    }

    er[cloud * NPTS + q] = (float)ratio;
}

// Reduce: mean over (b,n) of (er_x - er_y)^2 -> scalar.
__global__ __launch_bounds__(256) void reduce_kernel(const float* __restrict__ er,
                                                     float* __restrict__ out) {
    __shared__ double sbuf[256];
    double acc = 0.0;
    const int total = 2 * NPTS;  // (b, n) pairs
    for (int i = threadIdx.x; i < total; i += 256) {
        double d = (double)er[i] - (double)er[total + i];
        acc += d * d;
    }
    sbuf[threadIdx.x] = acc;
    __syncthreads();
    for (int s = 128; s > 0; s >>= 1) {
        if (threadIdx.x < s) sbuf[threadIdx.x] += sbuf[threadIdx.x + s];
        __syncthreads();
    }
    if (threadIdx.x == 0) out[0] = (float)(sbuf[0] / (double)total);
}

extern "C" void kernel_launch(void* const* d_in, const int* in_sizes, int n_in,
                              void* d_out, int out_size, void* d_ws, size_t ws_size,
                              hipStream_t stream) {
    const float* x = (const float*)d_in[0];
    const float* y = (const float*)d_in[1];
    float* er = (float*)d_ws;         // 4 * 8192 floats = 128 KiB scratch
    float* out = (float*)d_out;

    const int blocksPerCloud = NPTS / CHUNK;   // 64
    knn_eig_kernel<<<4 * blocksPerCloud, CHUNK, 0, stream>>>(x, y, er);
    reduce_kernel<<<1, 256, 0, stream>>>(er, out);
}

// Round 2
// 298.628 us; speedup vs baseline: 3.9979x; 3.9979x over previous
//
#include <hip/hip_runtime.h>
#include <hip/hip_bf16.h>
#include <math.h>

#define NPTS   8192
#define KNN    16
#define QCHUNK 128               // queries per block
#define NSEG   4                 // candidate segments per block
#define SEGLEN (NPTS / NSEG)     // 2048
#define NTHR   (QCHUNK * NSEG)   // 512 threads
#define BUFN   16                // per-lane LDS candidate buffer slots
#define UNR    8                 // candidate unroll (loads in flight)

// Pack [4][NPTS] float4 {x,y,z,|p|^2}. Clouds: 0=x[b0],1=x[b1],2=y[b0],3=y[b1].
__global__ __launch_bounds__(256) void prep_kernel(const float* __restrict__ x,
                                                   const float* __restrict__ y,
                                                   float4* __restrict__ P) {
    int i = blockIdx.x * 256 + threadIdx.x;
    if (i >= 4 * NPTS) return;
    int cloud = i >> 13;
    int p = i & (NPTS - 1);
    const float* s = (cloud < 2 ? x : y) + (size_t)(cloud & 1) * NPTS * 3;
    float a = s[p * 3 + 0];
    float b = s[p * 3 + 1];
    float c = s[p * 3 + 2];
    P[i] = make_float4(a, b, c, a * a + b * b + c * c);
}

__global__ __launch_bounds__(NTHR, 2) void knn_eig_kernel(
    const float4* __restrict__ P, float* __restrict__ er) {

    __shared__ float bufD[BUFN * NTHR];           // 32 KiB
    __shared__ int   bufI[BUFN * NTHR];           // 32 KiB
    __shared__ float mD[NSEG * KNN * QCHUNK];     // 32 KiB
    __shared__ int   mI[NSEG * KNN * QCHUNK];     // 32 KiB

    const int tid   = threadIdx.x;
    const int qlane = tid & (QCHUNK - 1);
    const int seg   = tid >> 7;
    const int cloud = blockIdx.x >> 6;
    const int chunk = blockIdx.x & 63;
    const int q     = chunk * QCHUNK + qlane;
    const float4* __restrict__ Pc = P + cloud * NPTS;

    const float4 qp = Pc[q];
    const float qx = qp.x, qy = qp.y, qz = qp.z, sqq = qp.w;

    // Sorted ascending top-16 (dist, idx) in registers.
    float dist[KNN]; int idx[KNN];
#pragma unroll
    for (int t = 0; t < KNN; ++t) { dist[t] = 3.4e38f; idx[t] = 0; }

    // Insert (v, vi) given precondition v < dist[KNN-1]; single bubble pass.
    auto ins = [&](float v, int vi) {
        dist[KNN - 1] = v; idx[KNN - 1] = vi;
#pragma unroll
        for (int t = KNN - 1; t > 0; --t) {
            float a = dist[t - 1], d = dist[t];
            bool c = d < a;                       // strict: ties keep earlier j
            dist[t]     = c ? a : d;
            dist[t - 1] = c ? d : a;
            int ia = idx[t - 1], id_ = idx[t];
            idx[t]     = c ? ia : id_;
            idx[t - 1] = c ? id_ : ia;
        }
    };

    int   cnt = 0;
    float thr = 3.4e38f;

    auto flush = [&]() {
#pragma unroll
        for (int b = 0; b < BUFN; ++b) {
            if (__any(b < cnt)) {
                float v  = bufD[b * NTHR + tid];
                int   vi = bufI[b * NTHR + tid];
                if (b < cnt && v < dist[KNN - 1]) ins(v, vi);
            }
        }
        cnt = 0;
        thr = dist[KNN - 1];
    };

    const int jbase = seg * SEGLEN;
    for (int j0 = 0; j0 < SEGLEN; j0 += UNR) {
        if (__any(cnt + UNR > BUFN)) flush();
        float4 c[UNR];
#pragma unroll
        for (int u = 0; u < UNR; ++u) c[u] = Pc[jbase + j0 + u];
#pragma unroll
        for (int u = 0; u < UNR; ++u) {
            float dot = qx * c[u].x + qy * c[u].y + qz * c[u].z;
            float d2  = (sqq + c[u].w) - 2.0f * dot;   // reference formula
            if (d2 < thr) {
                bufD[cnt * NTHR + tid] = d2;
                bufI[cnt * NTHR + tid] = jbase + j0 + u;
                cnt++;
            }
        }
    }
    flush();

    // Publish per-segment partials.
    __syncthreads();
#pragma unroll
    for (int e = 0; e < KNN; ++e) {
        mD[(seg * KNN + e) * QCHUNK + qlane] = dist[e];
        mI[(seg * KNN + e) * QCHUNK + qlane] = idx[e];
    }
    __syncthreads();

    if (seg != 0) return;

    // Merge segments 1..3 into seg0's registers (j-order preserves tie-break).
    for (int s = 1; s < NSEG; ++s) {
#pragma unroll
        for (int e = 0; e < KNN; ++e) {
            float v  = mD[(s * KNN + e) * QCHUNK + qlane];
            int   vi = mI[(s * KNN + e) * QCHUNK + qlane];
            if (v < dist[KNN - 1]) ins(v, vi);
        }
    }

    // Gather neighbors, mean, covariance (fp32 like reference).
    float nx[KNN], ny[KNN], nz[KNN];
    float mx = 0.f, my = 0.f, mz = 0.f;
#pragma unroll
    for (int t = 0; t < KNN; ++t) {
        float4 np_ = Pc[idx[t]];
        nx[t] = np_.x; ny[t] = np_.y; nz[t] = np_.z;
        mx += np_.x; my += np_.y; mz += np_.z;
    }
    mx *= (1.0f / KNN); my *= (1.0f / KNN); mz *= (1.0f / KNN);

    float c00 = 0.f, c01 = 0.f, c02 = 0.f, c11 = 0.f, c12 = 0.f, c22 = 0.f;
#pragma unroll
    for (int t = 0; t < KNN; ++t) {
        float dx = nx[t] - mx, dy = ny[t] - my, dz = nz[t] - mz;
        c00 += dx * dx; c01 += dx * dy; c02 += dx * dz;
        c11 += dy * dy; c12 += dy * dz; c22 += dz * dz;
    }
    const float invk = 1.0f / KNN;
    c00 *= invk; c01 *= invk; c02 *= invk;
    c11 *= invk; c12 *= invk; c22 *= invk;

    // Closed-form symmetric 3x3 eigenvalues (fp64 trigonometric method).
    double a00 = c00, a01 = c01, a02 = c02, a11 = c11, a12 = c12, a22 = c22;
    double qm = (a00 + a11 + a22) * (1.0 / 3.0);
    double p1 = a01 * a01 + a02 * a02 + a12 * a12;
    double b00 = a00 - qm, b11 = a11 - qm, b22 = a22 - qm;
    double p2 = b00 * b00 + b11 * b11 + b22 * b22 + 2.0 * p1;

    double ratio;
    if (p2 <= 0.0) {
        ratio = 1.0;
    } else {
        double p = sqrt(p2 * (1.0 / 6.0));
        double inv = 1.0 / p;
        double m00 = b00 * inv, m11 = b11 * inv, m22 = b22 * inv;
        double m01 = a01 * inv, m02 = a02 * inv, m12 = a12 * inv;
        double detB = m00 * (m11 * m22 - m12 * m12)
                    - m01 * (m01 * m22 - m12 * m02)
                    + m02 * (m01 * m12 - m11 * m02);
        double r = 0.5 * detB;
        r = fmin(1.0, fmax(-1.0, r));
        double phi = acos(r) * (1.0 / 3.0);
        double e1 = qm + 2.0 * p * cos(phi);
        double e3 = qm + 2.0 * p * cos(phi + 2.0943951023931953);
        double e2 = 3.0 * qm - e1 - e3;
        ratio = e1 / e2;
    }

    er[cloud * NPTS + q] = (float)ratio;
}

__global__ __launch_bounds__(256) void reduce_kernel(const float* __restrict__ er,
                                                     float* __restrict__ out) {
    __shared__ double sbuf[256];
    double acc = 0.0;
    const int total = 2 * NPTS;
    for (int i = threadIdx.x; i < total; i += 256) {
        double d = (double)er[i] - (double)er[total + i];
        acc += d * d;
    }
    sbuf[threadIdx.x] = acc;
    __syncthreads();
    for (int s = 128; s > 0; s >>= 1) {
        if (threadIdx.x < s) sbuf[threadIdx.x] += sbuf[threadIdx.x + s];
        __syncthreads();
    }
    if (threadIdx.x == 0) out[0] = (float)(sbuf[0] / (double)total);
}

extern "C" void kernel_launch(void* const* d_in, const int* in_sizes, int n_in,
                              void* d_out, int out_size, void* d_ws, size_t ws_size,
                              hipStream_t stream) {
    const float* x = (const float*)d_in[0];
    const float* y = (const float*)d_in[1];
    float4* P  = (float4*)d_ws;                                   // 512 KiB
    float*  er = (float*)((char*)d_ws + 4 * NPTS * sizeof(float4)); // +128 KiB
    float*  out = (float*)d_out;

    prep_kernel<<<(4 * NPTS + 255) / 256, 256, 0, stream>>>(x, y, P);
    knn_eig_kernel<<<4 * 64, NTHR, 0, stream>>>(P, er);
    reduce_kernel<<<1, 256, 0, stream>>>(er, out);
}

// Round 3
// 241.353 us; speedup vs baseline: 4.9466x; 1.2373x over previous
//
#include <hip/hip_runtime.h>
#include <hip/hip_bf16.h>
#include <math.h>

#define NPTS   8192
#define KNN    16
#define STAGE_PTS 2048           // candidates staged in LDS per stage (32 KiB)
#define NSTAGE (NPTS / STAGE_PTS)

// prev-lane value within each 16-lane row (DPP row_shr:1). Row-boundary lanes
// get the `old` operand (0) -- callers mask lane%16==0 explicitly.
__device__ __forceinline__ float dpp_prev_f(float v) {
    int r = __builtin_amdgcn_update_dpp(0, __float_as_int(v), 0x111, 0xF, 0xF, false);
    return __int_as_float(r);
}
__device__ __forceinline__ int dpp_prev_i(int v) {
    return __builtin_amdgcn_update_dpp(0, v, 0x111, 0xF, 0xF, false);
}

// One wave = one query. Lanes 0..15 of each 16-row hold the sorted top-16
// (all four rows evolve identically). Writes the 3x3 covariance (6 floats).
__global__ __launch_bounds__(256) void knn_cov_kernel(
    const float* __restrict__ x, const float* __restrict__ y,
    float* __restrict__ cov /* [4*NPTS][6] */) {

    __shared__ float4 tile[STAGE_PTS];   // {x,y,z,|p|^2}

    const int tid  = threadIdx.x;
    const int lane = tid & 63;
    const int wid  = (blockIdx.x << 2) | (tid >> 6);   // global query id, 0..32767
    const int cloud = wid >> 13;
    const int q     = wid & (NPTS - 1);
    const float* __restrict__ src = (cloud < 2 ? x : y) + (size_t)(cloud & 1) * NPTS * 3;

    const float qx = src[q * 3 + 0];
    const float qy = src[q * 3 + 1];
    const float qz = src[q * 3 + 2];

    float valV = 3.4e38f;   // distributed sorted list (ascending), shifted key d' = |p|^2 - 2 q.p
    int   idxV = 0;
    float thr  = 3.4e38f;   // current 16th-smallest (wave-uniform)

    for (int s = 0; s < NSTAGE; ++s) {
        __syncthreads();   // previous tile fully consumed
#pragma unroll
        for (int i = 0; i < STAGE_PTS / 256; ++i) {      // 8 iters, coalesced 12B/thread
            int t = tid + i * 256;
            int p = s * STAGE_PTS + t;
            float px = src[p * 3 + 0];
            float py = src[p * 3 + 1];
            float pz = src[p * 3 + 2];
            tile[t] = make_float4(px, py, pz, px * px + py * py + pz * pz);
        }
        __syncthreads();

        for (int c = 0; c < STAGE_PTS / 64; ++c) {       // 32 chunks of 64 candidates
            float4 f4 = tile[(c << 6) | lane];
            float dot = qx * f4.x + qy * f4.y + qz * f4.z;
            float d2  = __builtin_fmaf(-2.0f, dot, f4.w);   // shifted distance key
            unsigned long long m = __ballot(d2 < thr);
            if (m) {
                const int jb = s * STAGE_PTS + (c << 6);
                do {
                    int l = __builtin_ctzll(m);
                    m &= m - 1;
                    float sv = __int_as_float(
                        __builtin_amdgcn_readlane(__float_as_int(d2), l));
                    int sj = jb + l;
                    // shift-insert; exact no-op when sv >= valV[15]
                    float pv = dpp_prev_f(valV);
                    int   pi = dpp_prev_i(idxV);
                    bool keep  = (valV <= sv);                       // stability: equal keeps earlier j
                    bool fromv = ((lane & 15) == 0) || (pv <= sv);
                    float nv = keep ? valV : (fromv ? sv : pv);
                    int   ni = keep ? idxV : (fromv ? sj : pi);
                    valV = nv; idxV = ni;
                } while (m);
                thr = __int_as_float(
                    __builtin_amdgcn_readlane(__float_as_int(valV), 15));
            }
        }
    }

    // Gather neighbors (every lane holds one of the 16, replicated per row).
    float nx = src[idxV * 3 + 0];
    float ny = src[idxV * 3 + 1];
    float nz = src[idxV * 3 + 2];

    float mx = nx, my = ny, mz = nz;
#pragma unroll
    for (int w = 1; w < 16; w <<= 1) {
        mx += __shfl_xor(mx, w);
        my += __shfl_xor(my, w);
        mz += __shfl_xor(mz, w);
    }
    const float invk = 1.0f / KNN;
    mx *= invk; my *= invk; mz *= invk;

    float dx = nx - mx, dy = ny - my, dz = nz - mz;
    float c00 = dx * dx, c01 = dx * dy, c02 = dx * dz;
    float c11 = dy * dy, c12 = dy * dz, c22 = dz * dz;
#pragma unroll
    for (int w = 1; w < 16; w <<= 1) {
        c00 += __shfl_xor(c00, w); c01 += __shfl_xor(c01, w); c02 += __shfl_xor(c02, w);
        c11 += __shfl_xor(c11, w); c12 += __shfl_xor(c12, w); c22 += __shfl_xor(c22, w);
    }

    if (lane == 0) {
        float* cp = cov + (size_t)wid * 6;
        cp[0] = c00 * invk; cp[1] = c01 * invk; cp[2] = c02 * invk;
        cp[3] = c11 * invk; cp[4] = c12 * invk; cp[5] = c22 * invk;
    }
}

// Closed-form symmetric 3x3 eigenvalues (fp64), one query per thread.
__global__ __launch_bounds__(256) void eig_kernel(const float* __restrict__ cov,
                                                  float* __restrict__ er) {
    int i = blockIdx.x * 256 + threadIdx.x;
    if (i >= 4 * NPTS) return;
    const float* cp = cov + (size_t)i * 6;
    double a00 = cp[0], a01 = cp[1], a02 = cp[2];
    double a11 = cp[3], a12 = cp[4], a22 = cp[5];

    double qm = (a00 + a11 + a22) * (1.0 / 3.0);
    double p1 = a01 * a01 + a02 * a02 + a12 * a12;
    double b00 = a00 - qm, b11 = a11 - qm, b22 = a22 - qm;
    double p2 = b00 * b00 + b11 * b11 + b22 * b22 + 2.0 * p1;

    double ratio;
    if (p2 <= 0.0) {
        ratio = 1.0;
    } else {
        double p = sqrt(p2 * (1.0 / 6.0));
        double inv = 1.0 / p;
        double m00 = b00 * inv, m11 = b11 * inv, m22 = b22 * inv;
        double m01 = a01 * inv, m02 = a02 * inv, m12 = a12 * inv;
        double detB = m00 * (m11 * m22 - m12 * m12)
                    - m01 * (m01 * m22 - m12 * m02)
                    + m02 * (m01 * m12 - m11 * m02);
        double r = 0.5 * detB;
        r = fmin(1.0, fmax(-1.0, r));
        double phi = acos(r) * (1.0 / 3.0);
        double e1 = qm + 2.0 * p * cos(phi);
        double e3 = qm + 2.0 * p * cos(phi + 2.0943951023931953);
        double e2 = 3.0 * qm - e1 - e3;
        ratio = e1 / e2;
    }
    er[i] = (float)ratio;
}

__global__ __launch_bounds__(256) void reduce_kernel(const float* __restrict__ er,
                                                     float* __restrict__ out) {
    __shared__ double sbuf[256];
    double acc = 0.0;
    const int total = 2 * NPTS;
    for (int i = threadIdx.x; i < total; i += 256) {
        double d = (double)er[i] - (double)er[total + i];
        acc += d * d;
    }
    sbuf[threadIdx.x] = acc;
    __syncthreads();
    for (int s = 128; s > 0; s >>= 1) {
        if (threadIdx.x < s) sbuf[threadIdx.x] += sbuf[threadIdx.x + s];
        __syncthreads();
    }
    if (threadIdx.x == 0) out[0] = (float)(sbuf[0] / (double)total);
}

extern "C" void kernel_launch(void* const* d_in, const int* in_sizes, int n_in,
                              void* d_out, int out_size, void* d_ws, size_t ws_size,
                              hipStream_t stream) {
    const float* x = (const float*)d_in[0];
    const float* y = (const float*)d_in[1];
    float* cov = (float*)d_ws;                                  // 32768*6*4 = 768 KiB
    float* er  = (float*)((char*)d_ws + (size_t)4 * NPTS * 6 * sizeof(float)); // +128 KiB
    float* out = (float*)d_out;

    knn_cov_kernel<<<4 * NPTS / 4, 256, 0, stream>>>(x, y, cov);   // 8192 blocks, 1 query/wave
    eig_kernel<<<(4 * NPTS + 255) / 256, 256, 0, stream>>>(cov, er);
    reduce_kernel<<<1, 256, 0, stream>>>(er, out);
}